// Round 1
// baseline (633.575 us; speedup 1.0000x reference)
//
#include <hip/hip_runtime.h>

// Problem constants (fixed by the reference):
//   B=8, S=4096, D=1024, G=64, H_SEQ=2048, TOP_K=8
#define BB 8
#define SS 4096
#define DD 1024
#define D4 256           // D/4 float4s per row
#define GG 64
#define HH 2048
#define NCH 64           // H-chunks for the h reduction
#define SCALE 0.03125f   // D^-0.5 = 1/32
#define BSD (8L * 4096L * 1024L)

__device__ __forceinline__ float sigmoidf_(float x) {
    return 1.0f / (1.0f + expf(-x));
}

// ---------------------------------------------------------------------------
// Kernel A: partial sums of h over H chunks.
// grid = B*NCH blocks, 256 threads. Each block sums HH/NCH=32 rows of h[b].
// partial[(b*NCH+ch)*D + d]  (float4-vectorized)
// ---------------------------------------------------------------------------
__global__ __launch_bounds__(256) void reduce_h(const float* __restrict__ h,
                                                float* __restrict__ partial) {
    int blk = blockIdx.x;
    int b  = blk >> 6;      // / NCH
    int ch = blk & 63;      // % NCH
    int t  = threadIdx.x;   // 0..255 -> float4 index within row
    const float4* h4 = (const float4*)h;
    int sbase = ch * (HH / NCH);
    long base = ((long)b * HH + sbase) * D4 + t;
    float4 acc = make_float4(0.f, 0.f, 0.f, 0.f);
#pragma unroll 4
    for (int i = 0; i < HH / NCH; ++i) {
        float4 v = h4[base + (long)i * D4];
        acc.x += v.x; acc.y += v.y; acc.z += v.z; acc.w += v.w;
    }
    ((float4*)partial)[(long)blk * D4 + t] = acc;
}

// ---------------------------------------------------------------------------
// Kernel B: per-batch probe. 1 block per b, 256 threads (4 waves).
//  - finish q_probe from partials (LDS)
//  - logits over G=64 active rows (wave-parallel, 64-lane shuffle reduce)
//  - softmax, pred, surprise (for K and V)
//  - momentum update + gate projections -> ws, momentum -> d_out tail
// ---------------------------------------------------------------------------
__global__ __launch_bounds__(256) void probe_kernel(
        const float* __restrict__ K_curr, const float* __restrict__ V_curr,
        const float* __restrict__ momentum, const int* __restrict__ active_idx,
        const float* __restrict__ Wk, const float* __restrict__ bk,
        const float* __restrict__ Wv, const float* __restrict__ bv,
        const float* __restrict__ logit_eta, const float* __restrict__ alpha_logit,
        const float* __restrict__ partial,
        float* __restrict__ gate_k, float* __restrict__ gate_v,
        float* __restrict__ out_m) {
    int b = blockIdx.x;
    int t = threadIdx.x;
    int wave = t >> 6;
    int lane = t & 63;

    __shared__ float q[DD];
    __shared__ float lg[GG];
    __shared__ float attn[GG];
    __shared__ float red[4];
    __shared__ float s_sur[2];

    // ---- 1. q_probe = mean over H of h (finish from partials) ----
    float4 acc = make_float4(0.f, 0.f, 0.f, 0.f);
    const float4* p4 = (const float4*)partial;
#pragma unroll 8
    for (int ch = 0; ch < NCH; ++ch) {
        float4 v = p4[(long)(b * NCH + ch) * D4 + t];
        acc.x += v.x; acc.y += v.y; acc.z += v.z; acc.w += v.w;
    }
    const float invH = 1.0f / (float)HH;
    acc.x *= invH; acc.y *= invH; acc.z *= invH; acc.w *= invH;
    ((float4*)q)[t] = acc;
    __syncthreads();

    // ---- 2..4 for X in {K_active, V_active} ----
    for (int which = 0; which < 2; ++which) {
        const float* X = which ? V_curr : K_curr;

        // logits: each wave handles 16 g's; lane covers 16 d-elements
        for (int gi = 0; gi < 16; ++gi) {
            int g = wave * 16 + gi;
            int idx = active_idx[b * GG + g];
            const float* row = X + ((long)b * SS + idx) * DD;
            float s = 0.f;
#pragma unroll
            for (int j = 0; j < 16; ++j) {
                int d = lane + 64 * j;
                s += q[d] * row[d];
            }
#pragma unroll
            for (int off = 32; off >= 1; off >>= 1) s += __shfl_xor(s, off);
            if (lane == 0) lg[g] = s * SCALE;
        }
        __syncthreads();

        // softmax over 64 logits (wave 0 only)
        if (t < 64) {
            float x = lg[t];
            float m = x;
#pragma unroll
            for (int off = 32; off >= 1; off >>= 1) m = fmaxf(m, __shfl_xor(m, off));
            float e = expf(x - m);
            float ssum = e;
#pragma unroll
            for (int off = 32; off >= 1; off >>= 1) ssum += __shfl_xor(ssum, off);
            attn[t] = e / ssum;
        }
        __syncthreads();

        // pred = sum_g attn[g] * X[g], surprise = mean_d (pred - q)^2
        const float4* X4 = (const float4*)(X + (long)b * SS * DD);
        float4 pred = make_float4(0.f, 0.f, 0.f, 0.f);
        for (int g = 0; g < GG; ++g) {
            int idx = active_idx[b * GG + g];
            float a = attn[g];
            float4 xv = X4[(long)idx * D4 + t];
            pred.x += a * xv.x; pred.y += a * xv.y;
            pred.z += a * xv.z; pred.w += a * xv.w;
        }
        float4 qv = ((const float4*)q)[t];
        float dx = pred.x - qv.x, dy = pred.y - qv.y;
        float dz = pred.z - qv.z, dw = pred.w - qv.w;
        float ss = dx * dx + dy * dy + dz * dz + dw * dw;
#pragma unroll
        for (int off = 32; off >= 1; off >>= 1) ss += __shfl_xor(ss, off);
        if (lane == 0) red[wave] = ss;
        __syncthreads();
        if (t == 0) s_sur[which] = (red[0] + red[1] + red[2] + red[3]) / (float)DD;
        __syncthreads();
    }

    // ---- 5. momentum + gates ----
    float ks = s_sur[0], vs = s_sur[1];
    float alpha = sigmoidf_(alpha_logit[0]);
    float eta   = sigmoidf_(logit_eta[0]);
    float combined = alpha * ks + (1.0f - alpha) * vs;
    float new_m = eta * momentum[b] + (1.0f - eta) * combined;
    if (t == 0) out_m[b] = new_m;
    if (t < GG) {
        gate_k[b * GG + t] = sigmoidf_(Wk[t * 2 + 0] * ks + Wk[t * 2 + 1] * new_m + bk[t]);
        gate_v[b * GG + t] = sigmoidf_(Wv[t * 2 + 0] * vs + Wv[t * 2 + 1] * new_m + bv[t]);
    }
}

// ---------------------------------------------------------------------------
// Kernel C: bulk copy + gated blend of active rows. 1 block per (b,s) row,
// 256 threads (one float4 per thread per tensor). Membership search is
// block-uniform (no divergence): only 512/32768 blocks take the blend path.
// ---------------------------------------------------------------------------
__global__ __launch_bounds__(256) void scatter_copy(
        const float* __restrict__ K_curr, const float* __restrict__ V_curr,
        const float* __restrict__ K_prev, const float* __restrict__ V_prev,
        const int* __restrict__ active_idx,
        const float* __restrict__ gate_k, const float* __restrict__ gate_v,
        float* __restrict__ outK, float* __restrict__ outV) {
    int r = blockIdx.x;       // b*S + s
    int b = r >> 12;          // / 4096
    int s = r & 4095;
    int t = threadIdx.x;

    __shared__ int aidx[GG];
    if (t < GG) aidx[t] = active_idx[b * GG + t];
    __syncthreads();

    int g = -1;
#pragma unroll
    for (int j = 0; j < GG; ++j)
        if (aidx[j] == s) g = j;

    long off = (long)r * D4 + t;
    float4 kc = ((const float4*)K_curr)[off];
    float4 vc = ((const float4*)V_curr)[off];

    if (g >= 0) {
        float gk = gate_k[b * GG + g];
        float gv = gate_v[b * GG + g];
        float4 kp = ((const float4*)K_prev)[off];
        float4 vp = ((const float4*)V_prev)[off];
        kc.x = gk * kc.x + (1.0f - gk) * kp.x;
        kc.y = gk * kc.y + (1.0f - gk) * kp.y;
        kc.z = gk * kc.z + (1.0f - gk) * kp.z;
        kc.w = gk * kc.w + (1.0f - gk) * kp.w;
        vc.x = gv * vc.x + (1.0f - gv) * vp.x;
        vc.y = gv * vc.y + (1.0f - gv) * vp.y;
        vc.z = gv * vc.z + (1.0f - gv) * vp.z;
        vc.w = gv * vc.w + (1.0f - gv) * vp.w;
    }
    ((float4*)outK)[off] = kc;
    ((float4*)outV)[off] = vc;
}

extern "C" void kernel_launch(void* const* d_in, const int* in_sizes, int n_in,
                              void* d_out, int out_size, void* d_ws, size_t ws_size,
                              hipStream_t stream) {
    const float* K_curr      = (const float*)d_in[0];
    const float* V_curr      = (const float*)d_in[1];
    const float* K_prev      = (const float*)d_in[2];
    const float* V_prev      = (const float*)d_in[3];
    const float* h           = (const float*)d_in[4];
    const float* momentum    = (const float*)d_in[5];
    const int*   active_idx  = (const int*)d_in[6];
    const float* Wk          = (const float*)d_in[7];
    const float* bk          = (const float*)d_in[8];
    const float* Wv          = (const float*)d_in[9];
    const float* bv          = (const float*)d_in[10];
    const float* logit_eta   = (const float*)d_in[11];
    const float* alpha_logit = (const float*)d_in[12];

    float* out = (float*)d_out;
    float* ws  = (float*)d_ws;

    float* partial = ws;                        // B*NCH*D = 524288 floats (2 MB)
    float* gate_k  = ws + (long)BB * NCH * DD;  // 512 floats
    float* gate_v  = gate_k + BB * GG;          // 512 floats

    reduce_h<<<BB * NCH, 256, 0, stream>>>(h, partial);

    probe_kernel<<<BB, 256, 0, stream>>>(K_curr, V_curr, momentum, active_idx,
                                         Wk, bk, Wv, bv, logit_eta, alpha_logit,
                                         partial, gate_k, gate_v,
                                         out + 2 * BSD);

    scatter_copy<<<BB * SS, 256, 0, stream>>>(K_curr, V_curr, K_prev, V_prev,
                                              active_idx, gate_k, gate_v,
                                              out, out + BSD);
}